// Round 9
// baseline (434.691 us; speedup 1.0000x reference)
//
#include <hip/hip_runtime.h>
#include <hip/hip_bf16.h>
#include <stdint.h>

#define D 1024
#define NSUP 256
#define ROWS 16384      // 4*4096
#define MB 32           // rows per block
#define LTHREADS 512    // 8 waves
#define LGRID (ROWS / MB)   // 512 blocks -> 2 blocks/CU
#define LDS_BYTES 65536     // h tile only; w + scratch aliased into dead h rows
#define WBASE 49152         // w region = old-h rows 24-31 (16K)

typedef __attribute__((__ext_vector_type__(8))) __bf16 bf16x8;
typedef __attribute__((__ext_vector_type__(4))) float f32x4;

#define MFMA16(a, b, c) __builtin_amdgcn_mfma_f32_16x16x32_bf16((a), (b), (c), 0, 0, 0)

__device__ __forceinline__ uint32_t bfbits(float f) {
    __bf16 b = (__bf16)f;
    return (uint32_t)*(uint16_t*)&b;
}

__global__ void cast_k_kernel(const float* __restrict__ K, __bf16* __restrict__ Kb) {
    int i = (blockIdx.x * 256 + threadIdx.x) * 4;
    float4 v = *(const float4*)(K + i);
    __bf16 o[4] __attribute__((aligned(8)));
    o[0] = (__bf16)v.x; o[1] = (__bf16)v.y; o[2] = (__bf16)v.z; o[3] = (__bf16)v.w;
    *(uint2*)(Kb + i) = *(const uint2*)o;
}

// V [4][256][1024] f32 -> Vt [4][1024][256] bf16
__global__ void transpose_v_kernel(const float* __restrict__ V, __bf16* __restrict__ Vt) {
    __shared__ __bf16 tile[64][72];
    int l = blockIdx.z;
    int d0 = blockIdx.x * 64, n0 = blockIdx.y * 64;
    const float* Vl = V + (size_t)l * NSUP * D;
    __bf16* Vtl = Vt + (size_t)l * D * NSUP;
    for (int j = 0; j < 16; ++j) {
        int idx = j * 256 + threadIdx.x;
        int n_l = idx >> 6, d_l = idx & 63;
        tile[d_l][n_l] = (__bf16)Vl[(size_t)(n0 + n_l) * D + d0 + d_l];
    }
    __syncthreads();
    for (int j = 0; j < 16; ++j) {
        int idx = j * 256 + threadIdx.x;
        int d_l = idx >> 6, n_l = idx & 63;
        Vtl[(size_t)(d0 + d_l) * NSUP + n0 + n_l] = tile[d_l][n_l];
    }
}

// All 4 layers fused; h resident in LDS (bf16, XOR-swizzled rows, 64K total).
// 512 thr / 8 waves / 32 rows / LDS=64K -> 2 blocks per CU (128K usable cap:
// 51.7K->2 blk, 70K/80K->1 blk observed in rounds 1/3/8).
// Region aliasing: w[32][256]bf16 (16K) lives in OLD-h rows 24-31 (dead after
// Phase A); Phase C defers new-h rows 16-31 in packed-bf16 regs until w is
// consumed. exp partials use old-h row 0; sq-norm partials use dead w region.
// Layer 0: h staged pre-normalized (x chunk held in regs across the norm pass).
// Layers 1-3: h raw, rn folded into softmax scale.
// No softmax max-pass: |score*rn| <= |k_row| ~ 34 -> exp2 arg <= 50, f32-safe.
__global__ void __launch_bounds__(LTHREADS) __attribute__((amdgpu_waves_per_eu(4)))
fused4_kernel(const float* __restrict__ x, float* __restrict__ out,
              const __bf16* __restrict__ Kb, const __bf16* __restrict__ Vt) {
    extern __shared__ __align__(16) char pool[];
    const int tid = threadIdx.x;
    const int lane = tid & 63;
    const int wv = tid >> 6;            // wave 0..7
    const int llo = lane & 15, lhi = lane >> 4;
    const int swzk = (llo & 7) << 4;    // swizzle key for rows *16+llo
    const int row0 = blockIdx.x * MB;

    // ---- stage x -> NORMALIZED bf16 h (x chunk kept in regs; single HBM read) ----
    {
        const int srow = tid >> 4, c16 = tid & 15;
        const float* xr = x + (size_t)(row0 + srow) * D;
        const int sk = (srow & 7) << 4;
        float4 vv[16];
        float ss = 0.f;
        #pragma unroll
        for (int q = 0; q < 16; ++q) {
            vv[q] = *(const float4*)(xr + (c16 + q * 16) * 4);
            ss += vv[q].x * vv[q].x + vv[q].y * vv[q].y + vv[q].z * vv[q].z + vv[q].w * vv[q].w;
        }
        ss += __shfl_xor(ss, 1); ss += __shfl_xor(ss, 2);
        ss += __shfl_xor(ss, 4); ss += __shfl_xor(ss, 8);
        float rn = 1.f / (sqrtf(ss) + 1e-9f);
        #pragma unroll
        for (int q = 0; q < 16; ++q) {
            __bf16 t[4] __attribute__((aligned(8)));
            t[0] = (__bf16)(vv[q].x * rn); t[1] = (__bf16)(vv[q].y * rn);
            t[2] = (__bf16)(vv[q].z * rn); t[3] = (__bf16)(vv[q].w * rn);
            *(uint2*)(pool + srow * 2048 + (((c16 + q * 16) * 8) ^ sk)) = *(const uint2*)t;
        }
    }
    __syncthreads();

    float rnv[2][4];   // 1/|row| for current layer (unused at l=0: h pre-normalized)

    #pragma unroll 1
    for (int l = 0; l < 4; ++l) {
        // ---- Phase A: scores[32x256] = h @ K^T; wave cols [wv*32,+32) ----
        f32x4 acc[2][2];
        #pragma unroll
        for (int rf = 0; rf < 2; ++rf)
            #pragma unroll
            for (int cf = 0; cf < 2; ++cf)
                acc[rf][cf] = (f32x4){0.f, 0.f, 0.f, 0.f};
        const __bf16* kb0 = Kb + (size_t)l * NSUP * D + (size_t)(wv * 32 + llo) * D + lhi * 8;
        bf16x8 kbuf[2][2];
        #pragma unroll
        for (int cf = 0; cf < 2; ++cf)
            kbuf[0][cf] = *(const bf16x8*)(kb0 + (size_t)cf * 16 * D);
        #pragma unroll
        for (int k = 0; k < 32; ++k) {
            if (k < 31) {
                #pragma unroll
                for (int cf = 0; cf < 2; ++cf)
                    kbuf[(k + 1) & 1][cf] = *(const bf16x8*)(kb0 + (size_t)cf * 16 * D + (k + 1) * 32);
            }
            bf16x8 a0 = *(const bf16x8*)(pool + llo * 2048 + ((k * 64 + lhi * 16) ^ swzk));
            bf16x8 a1 = *(const bf16x8*)(pool + (16 + llo) * 2048 + ((k * 64 + lhi * 16) ^ swzk));
            #pragma unroll
            for (int cf = 0; cf < 2; ++cf) {
                acc[0][cf] = MFMA16(a0, kbuf[k & 1][cf], acc[0][cf]);
                acc[1][cf] = MFMA16(a1, kbuf[k & 1][cf], acc[1][cf]);
            }
        }
        __syncthreads();   // bar1: A done; old h dead

        // ---- Phase B: exp (rn folded; no max-pass) + wave partials in old-h row 0 ----
        float ee[2][2][4];
        #pragma unroll
        for (int rf = 0; rf < 2; ++rf)
            #pragma unroll
            for (int r = 0; r < 4; ++r) {
                float sc = (l == 0 ? 1.f : rnv[rf][r]) * 1.44269504f;
                float e0 = exp2f(acc[rf][0][r] * sc);
                float e1 = exp2f(acc[rf][1][r] * sc);
                ee[rf][0][r] = e0; ee[rf][1][r] = e1;
                float s = e0 + e1;
                s += __shfl_xor(s, 1); s += __shfl_xor(s, 2);
                s += __shfl_xor(s, 4); s += __shfl_xor(s, 8);
                if (llo == 0) *(float*)(pool + (rf * 16 + lhi * 4 + r) * 32 + wv * 4) = s;
            }
        __syncthreads();   // bar2: exp partials visible

        #pragma unroll
        for (int rf = 0; rf < 2; ++rf)
            #pragma unroll
            for (int r = 0; r < 4; ++r) {
                int row = rf * 16 + lhi * 4 + r;
                const f32x4* rp = (const f32x4*)(pool + row * 32);
                f32x4 s0 = rp[0], s1 = rp[1];
                float S = (s0[0] + s0[1] + s0[2] + s0[3]) + (s1[0] + s1[1] + s1[2] + s1[3]);
                float inv = 1.f / S;
                #pragma unroll
                for (int cf = 0; cf < 2; ++cf) {
                    int col = wv * 32 + cf * 16 + llo;
                    *(__bf16*)(pool + WBASE + row * 512 + ((col * 2) ^ ((row & 7) << 4))) =
                        (__bf16)(ee[rf][cf][r] * inv);
                }
            }
        __syncthreads();   // bar3: w visible

        // ---- Phase C: out[32x1024] = w @ V; wave d-cols [wv*128,+128) ----
        float sql[2][4];
        #pragma unroll
        for (int rf = 0; rf < 2; ++rf)
            #pragma unroll
            for (int r = 0; r < 4; ++r) sql[rf][r] = 0.f;
        uint32_t def[4][4];   // deferred rf=1 rows (16-31), bf16-packed (r even|odd<<16)

        #pragma unroll
        for (int ch = 0; ch < 4; ++ch) {
            f32x4 acc2[2][2];
            #pragma unroll
            for (int rf = 0; rf < 2; ++rf)
                #pragma unroll
                for (int c2 = 0; c2 < 2; ++c2)
                    acc2[rf][c2] = (f32x4){0.f, 0.f, 0.f, 0.f};
            const __bf16* vt0 = Vt + (size_t)l * D * NSUP
                              + (size_t)(wv * 128 + ch * 32 + llo) * NSUP + lhi * 8;
            bf16x8 vbuf[2][2];
            #pragma unroll
            for (int c2 = 0; c2 < 2; ++c2)
                vbuf[0][c2] = *(const bf16x8*)(vt0 + (size_t)c2 * 16 * NSUP);
            #pragma unroll
            for (int k = 0; k < 8; ++k) {
                if (k < 7) {
                    #pragma unroll
                    for (int c2 = 0; c2 < 2; ++c2)
                        vbuf[(k + 1) & 1][c2] = *(const bf16x8*)(vt0 + (size_t)c2 * 16 * NSUP + (k + 1) * 32);
                }
                bf16x8 a0 = *(const bf16x8*)(pool + WBASE + llo * 512 + ((k * 64 + lhi * 16) ^ swzk));
                bf16x8 a1 = *(const bf16x8*)(pool + WBASE + (16 + llo) * 512 + ((k * 64 + lhi * 16) ^ swzk));
                #pragma unroll
                for (int c2 = 0; c2 < 2; ++c2) {
                    acc2[0][c2] = MFMA16(a0, vbuf[k & 1][c2], acc2[0][c2]);
                    acc2[1][c2] = MFMA16(a1, vbuf[k & 1][c2], acc2[1][c2]);
                }
            }
            #pragma unroll
            for (int rf = 0; rf < 2; ++rf)
                #pragma unroll
                for (int c2 = 0; c2 < 2; ++c2)
                    #pragma unroll
                    for (int r = 0; r < 4; ++r)
                        sql[rf][r] += acc2[rf][c2][r] * acc2[rf][c2][r];
            if (l < 3) {
                // rows 0-15 immediate; rows 16-31 packed for deferred write
                #pragma unroll
                for (int c2 = 0; c2 < 2; ++c2) {
                    #pragma unroll
                    for (int r = 0; r < 4; ++r) {
                        int row = lhi * 4 + r;
                        int col = wv * 128 + ch * 32 + c2 * 16 + llo;
                        *(__bf16*)(pool + row * 2048 + ((col * 2) ^ ((row & 7) << 4))) =
                            (__bf16)acc2[0][c2][r];
                    }
                    def[ch][c2 * 2 + 0] = bfbits(acc2[1][c2][0]) | (bfbits(acc2[1][c2][1]) << 16);
                    def[ch][c2 * 2 + 1] = bfbits(acc2[1][c2][2]) | (bfbits(acc2[1][c2][3]) << 16);
                }
            } else {
                #pragma unroll
                for (int rf = 0; rf < 2; ++rf)
                    #pragma unroll
                    for (int c2 = 0; c2 < 2; ++c2)
                        #pragma unroll
                        for (int r = 0; r < 4; ++r) {
                            int row = rf * 16 + lhi * 4 + r;
                            int col = wv * 128 + ch * 32 + c2 * 16 + llo;
                            out[(size_t)(row0 + row) * D + col] = acc2[rf][c2][r];
                        }
            }
        }

        if (l < 3) {
            __syncthreads();   // bar4: all w reads done -> w region dead
            #pragma unroll
            for (int rf = 0; rf < 2; ++rf)
                #pragma unroll
                for (int r = 0; r < 4; ++r) {
                    float s = sql[rf][r];
                    s += __shfl_xor(s, 1); s += __shfl_xor(s, 2);
                    s += __shfl_xor(s, 4); s += __shfl_xor(s, 8);
                    if (llo == 0)
                        *(float*)(pool + WBASE + (rf * 16 + lhi * 4 + r) * 32 + wv * 4) = s;
                }
            __syncthreads();   // bar5: sq partials visible
            #pragma unroll
            for (int rf = 0; rf < 2; ++rf)
                #pragma unroll
                for (int r = 0; r < 4; ++r) {
                    const f32x4* rp = (const f32x4*)(pool + WBASE + (rf * 16 + lhi * 4 + r) * 32);
                    f32x4 s0 = rp[0], s1 = rp[1];
                    float ss = (s0[0] + s0[1] + s0[2] + s0[3]) + (s1[0] + s1[1] + s1[2] + s1[3]);
                    rnv[rf][r] = 1.f / (sqrtf(ss) + 1e-9f);
                }
            __syncthreads();   // bar6: sq reads done -> region writable
            // deferred new-h rows 16-31 (includes old w region)
            #pragma unroll
            for (int ch = 0; ch < 4; ++ch)
                #pragma unroll
                for (int c2 = 0; c2 < 2; ++c2)
                    #pragma unroll
                    for (int rp = 0; rp < 2; ++rp) {
                        uint32_t pk = def[ch][c2 * 2 + rp];
                        int re = 16 + lhi * 4 + rp * 2;
                        int ro = re + 1;
                        int col = wv * 128 + ch * 32 + c2 * 16 + llo;
                        *(uint16_t*)(pool + re * 2048 + ((col * 2) ^ ((re & 7) << 4))) =
                            (uint16_t)(pk & 0xffff);
                        *(uint16_t*)(pool + ro * 2048 + ((col * 2) ^ ((ro & 7) << 4))) =
                            (uint16_t)(pk >> 16);
                    }
            __syncthreads();   // bar7: h complete for next layer
        }
    }
}

extern "C" void kernel_launch(void* const* d_in, const int* in_sizes, int n_in,
                              void* d_out, int out_size, void* d_ws, size_t ws_size,
                              hipStream_t stream) {
    const float* x = (const float*)d_in[0];
    const float* keys = (const float*)d_in[1];
    const float* values = (const float*)d_in[2];
    float* out = (float*)d_out;

    char* ws = (char*)d_ws;
    __bf16* Kb = (__bf16*)(ws);             // 4*256*1024*2 = 2 MB
    __bf16* Vt = (__bf16*)(ws + 2097152);   // 4*1024*256*2 = 2 MB

    (void)hipFuncSetAttribute((const void*)fused4_kernel,
                              hipFuncAttributeMaxDynamicSharedMemorySize, LDS_BYTES);

    cast_k_kernel<<<1024, 256, 0, stream>>>(keys, Kb);
    transpose_v_kernel<<<dim3(16, 4, 4), 256, 0, stream>>>(values, Vt);
    fused4_kernel<<<LGRID, LTHREADS, LDS_BYTES, stream>>>(x, out, Kb, Vt);
}

// Round 10
// 406.810 us; speedup vs baseline: 1.0685x; 1.0685x over previous
//
#include <hip/hip_runtime.h>
#include <hip/hip_bf16.h>
#include <stdint.h>

#define D 1024
#define NSUP 256
#define ROWS 16384      // 4*4096
#define MB 32           // rows per block
#define LTHREADS 512    // 8 waves
#define LGRID (ROWS / MB)   // 512 blocks -> 2 blocks/CU
#define LDS_BYTES 65536     // h tile only; w + scratch aliased into dead h rows
#define WBASE 49152         // w region = old-h rows 24-31 (16K)

typedef __attribute__((__ext_vector_type__(8))) __bf16 bf16x8;
typedef __attribute__((__ext_vector_type__(4))) float f32x4;

#define MFMA16(a, b, c) __builtin_amdgcn_mfma_f32_16x16x32_bf16((a), (b), (c), 0, 0, 0)

__device__ __forceinline__ uint32_t bfbits(float f) {
    __bf16 b = (__bf16)f;
    return (uint32_t)*(uint16_t*)&b;
}

__global__ void cast_k_kernel(const float* __restrict__ K, __bf16* __restrict__ Kb) {
    int i = (blockIdx.x * 256 + threadIdx.x) * 4;
    float4 v = *(const float4*)(K + i);
    __bf16 o[4] __attribute__((aligned(8)));
    o[0] = (__bf16)v.x; o[1] = (__bf16)v.y; o[2] = (__bf16)v.z; o[3] = (__bf16)v.w;
    *(uint2*)(Kb + i) = *(const uint2*)o;
}

// V [4][256][1024] f32 -> Vt [4][1024][256] bf16
__global__ void transpose_v_kernel(const float* __restrict__ V, __bf16* __restrict__ Vt) {
    __shared__ __bf16 tile[64][72];
    int l = blockIdx.z;
    int d0 = blockIdx.x * 64, n0 = blockIdx.y * 64;
    const float* Vl = V + (size_t)l * NSUP * D;
    __bf16* Vtl = Vt + (size_t)l * D * NSUP;
    for (int j = 0; j < 16; ++j) {
        int idx = j * 256 + threadIdx.x;
        int n_l = idx >> 6, d_l = idx & 63;
        tile[d_l][n_l] = (__bf16)Vl[(size_t)(n0 + n_l) * D + d0 + d_l];
    }
    __syncthreads();
    for (int j = 0; j < 16; ++j) {
        int idx = j * 256 + threadIdx.x;
        int d_l = idx >> 6, n_l = idx & 63;
        Vtl[(size_t)(d0 + d_l) * NSUP + n0 + n_l] = tile[d_l][n_l];
    }
}

// All 4 layers fused; h resident in LDS (bf16, XOR-swizzled rows, 64K total).
// 512 thr / 8 waves / 32 rows / LDS=64K -> 2 blocks per CU.
// Region aliasing: w[32][256]bf16 (16K) lives in OLD-h rows 24-31 (dead after
// Phase A); Phase C defers new-h rows 16-31 in packed-bf16 regs until w is
// consumed. exp partials use old-h row 0; sq-norm partials use dead w region.
// Layer 0: h staged pre-normalized (x chunk held in regs across the norm pass).
// Layers 1-3: h raw, rn folded into softmax scale.
// No softmax max-pass: |score*rn| <= |k_row| ~ 34 -> exp2 arg <= 50, f32-safe.
// REGISTER RULE (rounds 3-9): plain __launch_bounds__(512) ONLY. Any occupancy
// attribute (launch_bounds 2nd arg, amdgpu_waves_per_eu) pins VGPR=64 on this
// toolchain and causes catastrophic scratch spills (FETCH/WRITE +350 MB each).
__global__ void __launch_bounds__(LTHREADS)
fused4_kernel(const float* __restrict__ x, float* __restrict__ out,
              const __bf16* __restrict__ Kb, const __bf16* __restrict__ Vt) {
    extern __shared__ __align__(16) char pool[];
    const int tid = threadIdx.x;
    const int lane = tid & 63;
    const int wv = tid >> 6;            // wave 0..7
    const int llo = lane & 15, lhi = lane >> 4;
    const int swzk = (llo & 7) << 4;    // swizzle key for rows *16+llo
    const int row0 = blockIdx.x * MB;

    // ---- stage x -> NORMALIZED bf16 h (x chunk kept in regs; single HBM read) ----
    {
        const int srow = tid >> 4, c16 = tid & 15;
        const float* xr = x + (size_t)(row0 + srow) * D;
        const int sk = (srow & 7) << 4;
        float4 vv[16];
        float ss = 0.f;
        #pragma unroll
        for (int q = 0; q < 16; ++q) {
            vv[q] = *(const float4*)(xr + (c16 + q * 16) * 4);
            ss += vv[q].x * vv[q].x + vv[q].y * vv[q].y + vv[q].z * vv[q].z + vv[q].w * vv[q].w;
        }
        ss += __shfl_xor(ss, 1); ss += __shfl_xor(ss, 2);
        ss += __shfl_xor(ss, 4); ss += __shfl_xor(ss, 8);
        float rn = 1.f / (sqrtf(ss) + 1e-9f);
        #pragma unroll
        for (int q = 0; q < 16; ++q) {
            __bf16 t[4] __attribute__((aligned(8)));
            t[0] = (__bf16)(vv[q].x * rn); t[1] = (__bf16)(vv[q].y * rn);
            t[2] = (__bf16)(vv[q].z * rn); t[3] = (__bf16)(vv[q].w * rn);
            *(uint2*)(pool + srow * 2048 + (((c16 + q * 16) * 8) ^ sk)) = *(const uint2*)t;
        }
    }
    __syncthreads();

    float rnv[2][4];   // 1/|row| for current layer (unused at l=0: h pre-normalized)

    #pragma unroll 1
    for (int l = 0; l < 4; ++l) {
        // ---- Phase A: scores[32x256] = h @ K^T; wave cols [wv*32,+32) ----
        f32x4 acc[2][2];
        #pragma unroll
        for (int rf = 0; rf < 2; ++rf)
            #pragma unroll
            for (int cf = 0; cf < 2; ++cf)
                acc[rf][cf] = (f32x4){0.f, 0.f, 0.f, 0.f};
        const __bf16* kb0 = Kb + (size_t)l * NSUP * D + (size_t)(wv * 32 + llo) * D + lhi * 8;
        bf16x8 kbuf[2][2];
        #pragma unroll
        for (int cf = 0; cf < 2; ++cf)
            kbuf[0][cf] = *(const bf16x8*)(kb0 + (size_t)cf * 16 * D);
        #pragma unroll
        for (int k = 0; k < 32; ++k) {
            if (k < 31) {
                #pragma unroll
                for (int cf = 0; cf < 2; ++cf)
                    kbuf[(k + 1) & 1][cf] = *(const bf16x8*)(kb0 + (size_t)cf * 16 * D + (k + 1) * 32);
            }
            bf16x8 a0 = *(const bf16x8*)(pool + llo * 2048 + ((k * 64 + lhi * 16) ^ swzk));
            bf16x8 a1 = *(const bf16x8*)(pool + (16 + llo) * 2048 + ((k * 64 + lhi * 16) ^ swzk));
            #pragma unroll
            for (int cf = 0; cf < 2; ++cf) {
                acc[0][cf] = MFMA16(a0, kbuf[k & 1][cf], acc[0][cf]);
                acc[1][cf] = MFMA16(a1, kbuf[k & 1][cf], acc[1][cf]);
            }
        }
        __syncthreads();   // bar1: A done; old h dead

        // ---- Phase B: exp (rn folded; no max-pass) + wave partials in old-h row 0 ----
        float ee[2][2][4];
        #pragma unroll
        for (int rf = 0; rf < 2; ++rf)
            #pragma unroll
            for (int r = 0; r < 4; ++r) {
                float sc = (l == 0 ? 1.f : rnv[rf][r]) * 1.44269504f;
                float e0 = exp2f(acc[rf][0][r] * sc);
                float e1 = exp2f(acc[rf][1][r] * sc);
                ee[rf][0][r] = e0; ee[rf][1][r] = e1;
                float s = e0 + e1;
                s += __shfl_xor(s, 1); s += __shfl_xor(s, 2);
                s += __shfl_xor(s, 4); s += __shfl_xor(s, 8);
                if (llo == 0) *(float*)(pool + (rf * 16 + lhi * 4 + r) * 32 + wv * 4) = s;
            }
        __syncthreads();   // bar2: exp partials visible

        #pragma unroll
        for (int rf = 0; rf < 2; ++rf)
            #pragma unroll
            for (int r = 0; r < 4; ++r) {
                int row = rf * 16 + lhi * 4 + r;
                const f32x4* rp = (const f32x4*)(pool + row * 32);
                f32x4 s0 = rp[0], s1 = rp[1];
                float S = (s0[0] + s0[1] + s0[2] + s0[3]) + (s1[0] + s1[1] + s1[2] + s1[3]);
                float inv = 1.f / S;
                #pragma unroll
                for (int cf = 0; cf < 2; ++cf) {
                    int col = wv * 32 + cf * 16 + llo;
                    *(__bf16*)(pool + WBASE + row * 512 + ((col * 2) ^ ((row & 7) << 4))) =
                        (__bf16)(ee[rf][cf][r] * inv);
                }
            }
        __syncthreads();   // bar3: w visible

        // ---- Phase C: out[32x1024] = w @ V; wave d-cols [wv*128,+128) ----
        float sql[2][4];
        #pragma unroll
        for (int rf = 0; rf < 2; ++rf)
            #pragma unroll
            for (int r = 0; r < 4; ++r) sql[rf][r] = 0.f;
        uint32_t def[4][4];   // deferred rf=1 rows (16-31), bf16-packed (r even|odd<<16)

        #pragma unroll
        for (int ch = 0; ch < 4; ++ch) {
            f32x4 acc2[2][2];
            #pragma unroll
            for (int rf = 0; rf < 2; ++rf)
                #pragma unroll
                for (int c2 = 0; c2 < 2; ++c2)
                    acc2[rf][c2] = (f32x4){0.f, 0.f, 0.f, 0.f};
            const __bf16* vt0 = Vt + (size_t)l * D * NSUP
                              + (size_t)(wv * 128 + ch * 32 + llo) * NSUP + lhi * 8;
            bf16x8 vbuf[2][2];
            #pragma unroll
            for (int c2 = 0; c2 < 2; ++c2)
                vbuf[0][c2] = *(const bf16x8*)(vt0 + (size_t)c2 * 16 * NSUP);
            #pragma unroll
            for (int k = 0; k < 8; ++k) {
                if (k < 7) {
                    #pragma unroll
                    for (int c2 = 0; c2 < 2; ++c2)
                        vbuf[(k + 1) & 1][c2] = *(const bf16x8*)(vt0 + (size_t)c2 * 16 * NSUP + (k + 1) * 32);
                }
                bf16x8 a0 = *(const bf16x8*)(pool + WBASE + llo * 512 + ((k * 64 + lhi * 16) ^ swzk));
                bf16x8 a1 = *(const bf16x8*)(pool + WBASE + (16 + llo) * 512 + ((k * 64 + lhi * 16) ^ swzk));
                #pragma unroll
                for (int c2 = 0; c2 < 2; ++c2) {
                    acc2[0][c2] = MFMA16(a0, vbuf[k & 1][c2], acc2[0][c2]);
                    acc2[1][c2] = MFMA16(a1, vbuf[k & 1][c2], acc2[1][c2]);
                }
            }
            #pragma unroll
            for (int rf = 0; rf < 2; ++rf)
                #pragma unroll
                for (int c2 = 0; c2 < 2; ++c2)
                    #pragma unroll
                    for (int r = 0; r < 4; ++r)
                        sql[rf][r] += acc2[rf][c2][r] * acc2[rf][c2][r];
            if (l < 3) {
                // rows 0-15 immediate; rows 16-31 packed for deferred write
                #pragma unroll
                for (int c2 = 0; c2 < 2; ++c2) {
                    #pragma unroll
                    for (int r = 0; r < 4; ++r) {
                        int row = lhi * 4 + r;
                        int col = wv * 128 + ch * 32 + c2 * 16 + llo;
                        *(__bf16*)(pool + row * 2048 + ((col * 2) ^ ((row & 7) << 4))) =
                            (__bf16)acc2[0][c2][r];
                    }
                    def[ch][c2 * 2 + 0] = bfbits(acc2[1][c2][0]) | (bfbits(acc2[1][c2][1]) << 16);
                    def[ch][c2 * 2 + 1] = bfbits(acc2[1][c2][2]) | (bfbits(acc2[1][c2][3]) << 16);
                }
            } else {
                #pragma unroll
                for (int rf = 0; rf < 2; ++rf)
                    #pragma unroll
                    for (int c2 = 0; c2 < 2; ++c2)
                        #pragma unroll
                        for (int r = 0; r < 4; ++r) {
                            int row = rf * 16 + lhi * 4 + r;
                            int col = wv * 128 + ch * 32 + c2 * 16 + llo;
                            out[(size_t)(row0 + row) * D + col] = acc2[rf][c2][r];
                        }
            }
        }

        if (l < 3) {
            __syncthreads();   // bar4: all w reads done -> w region dead
            #pragma unroll
            for (int rf = 0; rf < 2; ++rf)
                #pragma unroll
                for (int r = 0; r < 4; ++r) {
                    float s = sql[rf][r];
                    s += __shfl_xor(s, 1); s += __shfl_xor(s, 2);
                    s += __shfl_xor(s, 4); s += __shfl_xor(s, 8);
                    if (llo == 0)
                        *(float*)(pool + WBASE + (rf * 16 + lhi * 4 + r) * 32 + wv * 4) = s;
                }
            __syncthreads();   // bar5: sq partials visible
            #pragma unroll
            for (int rf = 0; rf < 2; ++rf)
                #pragma unroll
                for (int r = 0; r < 4; ++r) {
                    const f32x4* rp = (const f32x4*)(pool + WBASE + (rf * 16 + lhi * 4 + r) * 32);
                    f32x4 s0 = rp[0], s1 = rp[1];
                    float ss = (s0[0] + s0[1] + s0[2] + s0[3]) + (s1[0] + s1[1] + s1[2] + s1[3]);
                    rnv[rf][r] = 1.f / (sqrtf(ss) + 1e-9f);
                }
            __syncthreads();   // bar6: sq reads done -> region writable
            // deferred new-h rows 16-31 (includes old w region)
            #pragma unroll
            for (int ch = 0; ch < 4; ++ch)
                #pragma unroll
                for (int c2 = 0; c2 < 2; ++c2)
                    #pragma unroll
                    for (int rp = 0; rp < 2; ++rp) {
                        uint32_t pk = def[ch][c2 * 2 + rp];
                        int re = 16 + lhi * 4 + rp * 2;
                        int ro = re + 1;
                        int col = wv * 128 + ch * 32 + c2 * 16 + llo;
                        *(uint16_t*)(pool + re * 2048 + ((col * 2) ^ ((re & 7) << 4))) =
                            (uint16_t)(pk & 0xffff);
                        *(uint16_t*)(pool + ro * 2048 + ((col * 2) ^ ((ro & 7) << 4))) =
                            (uint16_t)(pk >> 16);
                    }
            __syncthreads();   // bar7: h complete for next layer
        }
    }
}

extern "C" void kernel_launch(void* const* d_in, const int* in_sizes, int n_in,
                              void* d_out, int out_size, void* d_ws, size_t ws_size,
                              hipStream_t stream) {
    const float* x = (const float*)d_in[0];
    const float* keys = (const float*)d_in[1];
    const float* values = (const float*)d_in[2];
    float* out = (float*)d_out;

    char* ws = (char*)d_ws;
    __bf16* Kb = (__bf16*)(ws);             // 4*256*1024*2 = 2 MB
    __bf16* Vt = (__bf16*)(ws + 2097152);   // 4*1024*256*2 = 2 MB

    (void)hipFuncSetAttribute((const void*)fused4_kernel,
                              hipFuncAttributeMaxDynamicSharedMemorySize, LDS_BYTES);

    cast_k_kernel<<<1024, 256, 0, stream>>>(keys, Kb);
    transpose_v_kernel<<<dim3(16, 4, 4), 256, 0, stream>>>(values, Vt);
    fused4_kernel<<<LGRID, LTHREADS, LDS_BYTES, stream>>>(x, out, Kb, Vt);
}

// Round 11
// 324.920 us; speedup vs baseline: 1.3378x; 1.2520x over previous
//
#include <hip/hip_runtime.h>
#include <hip/hip_bf16.h>
#include <stdint.h>

#define D 1024
#define NSUP 256
#define ROWS 16384      // 4*4096
#define MB 32           // rows per block
#define LTHREADS 512    // 8 waves
#define LGRID (ROWS / MB)   // 512 blocks
#define WBASE 49152         // w region = old-h rows 24-31 (16K)

typedef __attribute__((__ext_vector_type__(8))) __bf16 bf16x8;
typedef __attribute__((__ext_vector_type__(4))) float f32x4;

#define MFMA16(a, b, c) __builtin_amdgcn_mfma_f32_16x16x32_bf16((a), (b), (c), 0, 0, 0)

__device__ __forceinline__ uint32_t bfbits(float f) {
    __bf16 b = (__bf16)f;
    return (uint32_t)*(uint16_t*)&b;
}

__global__ void cast_k_kernel(const float* __restrict__ K, __bf16* __restrict__ Kb) {
    int i = (blockIdx.x * 256 + threadIdx.x) * 4;
    float4 v = *(const float4*)(K + i);
    __bf16 o[4] __attribute__((aligned(8)));
    o[0] = (__bf16)v.x; o[1] = (__bf16)v.y; o[2] = (__bf16)v.z; o[3] = (__bf16)v.w;
    *(uint2*)(Kb + i) = *(const uint2*)o;
}

// V [4][256][1024] f32 -> Vt [4][1024][256] bf16
__global__ void transpose_v_kernel(const float* __restrict__ V, __bf16* __restrict__ Vt) {
    __shared__ __bf16 tile[64][72];
    int l = blockIdx.z;
    int d0 = blockIdx.x * 64, n0 = blockIdx.y * 64;
    const float* Vl = V + (size_t)l * NSUP * D;
    __bf16* Vtl = Vt + (size_t)l * D * NSUP;
    for (int j = 0; j < 16; ++j) {
        int idx = j * 256 + threadIdx.x;
        int n_l = idx >> 6, d_l = idx & 63;
        tile[d_l][n_l] = (__bf16)Vl[(size_t)(n0 + n_l) * D + d0 + d_l];
    }
    __syncthreads();
    for (int j = 0; j < 16; ++j) {
        int idx = j * 256 + threadIdx.x;
        int d_l = idx >> 6, n_l = idx & 63;
        Vtl[(size_t)(d0 + d_l) * NSUP + n0 + n_l] = tile[d_l][n_l];
    }
}

// All 4 layers fused; h resident in STATIC 64K LDS (bf16, XOR-swizzled rows).
// 512 thr / 8 waves / 32 rows. Static (not dynamic) 65536B pool: hypothesis is
// dynamic-LDS carries per-block overhead that pushed 2x64K past the ~128K
// usable cap (51712->2blk, 65536 dyn->1blk observed).
// Region aliasing: w[32][256]bf16 (16K) at WBASE = old-h rows 24-31 (dead
// after Phase A); Phase C writes new-h rows 0-15 immediately, defers rows
// 16-31 packed-bf16 in regs until w consumed. exp partials in old-h row 0;
// sq partials in dead w region.
// Layer 0: h staged pre-normalized via TWO-PASS x read (pass1 sq-norm w/ ~8
// live regs, pass2 re-read from L2 + scale) -- avoids the 64-reg vv[16] blob.
// Layers 1-3: h raw, rn folded into softmax scale. No softmax max-pass:
// |score*rn| <= |k_row| ~ 34 -> exp2 arg <= 50, f32-safe.
// K/V streamed from L2 through depth-4 register rings (static idx (k+3)&3).
// REGISTER RULE (rounds 3-10): plain __launch_bounds__(512) ONLY; any
// occupancy attribute pins VGPR=64 and spills.
__global__ void __launch_bounds__(LTHREADS)
fused4_kernel(const float* __restrict__ x, float* __restrict__ out,
              const __bf16* __restrict__ Kb, const __bf16* __restrict__ Vt) {
    __shared__ __align__(16) char pool[65536];
    const int tid = threadIdx.x;
    const int lane = tid & 63;
    const int wv = tid >> 6;            // wave 0..7
    const int llo = lane & 15, lhi = lane >> 4;
    const int swzk = (llo & 7) << 4;    // swizzle key for rows *16+llo
    const int row0 = blockIdx.x * MB;

    // ---- stage x -> NORMALIZED bf16 h, two-pass (low register pressure) ----
    {
        const int srow = tid >> 4, c16 = tid & 15;
        const float* xr = x + (size_t)(row0 + srow) * D;
        const int sk = (srow & 7) << 4;
        float ss = 0.f;
        #pragma unroll
        for (int q = 0; q < 16; ++q) {
            float4 v = *(const float4*)(xr + (c16 + q * 16) * 4);
            ss += v.x * v.x + v.y * v.y + v.z * v.z + v.w * v.w;
        }
        ss += __shfl_xor(ss, 1); ss += __shfl_xor(ss, 2);
        ss += __shfl_xor(ss, 4); ss += __shfl_xor(ss, 8);
        float rn = 1.f / (sqrtf(ss) + 1e-9f);
        asm volatile("" ::: "memory");   // block CSE of pass-2 loads into pass-1 regs
        #pragma unroll
        for (int q = 0; q < 16; ++q) {
            float4 v = *(const float4*)(xr + (c16 + q * 16) * 4);
            __bf16 t[4] __attribute__((aligned(8)));
            t[0] = (__bf16)(v.x * rn); t[1] = (__bf16)(v.y * rn);
            t[2] = (__bf16)(v.z * rn); t[3] = (__bf16)(v.w * rn);
            *(uint2*)(pool + srow * 2048 + (((c16 + q * 16) * 8) ^ sk)) = *(const uint2*)t;
        }
    }
    __syncthreads();

    float rnv[2][4];   // 1/|row| for current layer (unused at l=0: h pre-normalized)

    #pragma unroll 1
    for (int l = 0; l < 4; ++l) {
        // ---- Phase A: scores[32x256] = h @ K^T; wave cols [wv*32,+32) ----
        f32x4 acc[2][2];
        #pragma unroll
        for (int rf = 0; rf < 2; ++rf)
            #pragma unroll
            for (int cf = 0; cf < 2; ++cf)
                acc[rf][cf] = (f32x4){0.f, 0.f, 0.f, 0.f};
        const __bf16* kb0 = Kb + (size_t)l * NSUP * D + (size_t)(wv * 32 + llo) * D + lhi * 8;
        bf16x8 kb[4][2];
        #pragma unroll
        for (int p = 0; p < 3; ++p)
            #pragma unroll
            for (int cf = 0; cf < 2; ++cf)
                kb[p][cf] = *(const bf16x8*)(kb0 + (size_t)cf * 16 * D + p * 32);
        #pragma unroll
        for (int k = 0; k < 32; ++k) {
            if (k < 29) {
                #pragma unroll
                for (int cf = 0; cf < 2; ++cf)
                    kb[(k + 3) & 3][cf] = *(const bf16x8*)(kb0 + (size_t)cf * 16 * D + (k + 3) * 32);
            }
            bf16x8 a0 = *(const bf16x8*)(pool + llo * 2048 + ((k * 64 + lhi * 16) ^ swzk));
            bf16x8 a1 = *(const bf16x8*)(pool + (16 + llo) * 2048 + ((k * 64 + lhi * 16) ^ swzk));
            #pragma unroll
            for (int cf = 0; cf < 2; ++cf) {
                acc[0][cf] = MFMA16(a0, kb[k & 3][cf], acc[0][cf]);
                acc[1][cf] = MFMA16(a1, kb[k & 3][cf], acc[1][cf]);
            }
        }
        __syncthreads();   // bar1: A done; old h dead

        // ---- Phase B: exp (rn folded; no max-pass) + wave partials in old-h row 0 ----
        float ee[2][2][4];
        #pragma unroll
        for (int rf = 0; rf < 2; ++rf)
            #pragma unroll
            for (int r = 0; r < 4; ++r) {
                float sc = (l == 0 ? 1.f : rnv[rf][r]) * 1.44269504f;
                float e0 = exp2f(acc[rf][0][r] * sc);
                float e1 = exp2f(acc[rf][1][r] * sc);
                ee[rf][0][r] = e0; ee[rf][1][r] = e1;
                float s = e0 + e1;
                s += __shfl_xor(s, 1); s += __shfl_xor(s, 2);
                s += __shfl_xor(s, 4); s += __shfl_xor(s, 8);
                if (llo == 0) *(float*)(pool + (rf * 16 + lhi * 4 + r) * 32 + wv * 4) = s;
            }
        __syncthreads();   // bar2: exp partials visible

        #pragma unroll
        for (int rf = 0; rf < 2; ++rf)
            #pragma unroll
            for (int r = 0; r < 4; ++r) {
                int row = rf * 16 + lhi * 4 + r;
                const f32x4* rp = (const f32x4*)(pool + row * 32);
                f32x4 s0 = rp[0], s1 = rp[1];
                float S = (s0[0] + s0[1] + s0[2] + s0[3]) + (s1[0] + s1[1] + s1[2] + s1[3]);
                float inv = 1.f / S;
                #pragma unroll
                for (int cf = 0; cf < 2; ++cf) {
                    int col = wv * 32 + cf * 16 + llo;
                    *(__bf16*)(pool + WBASE + row * 512 + ((col * 2) ^ ((row & 7) << 4))) =
                        (__bf16)(ee[rf][cf][r] * inv);
                }
            }
        __syncthreads();   // bar3: w visible

        // ---- Phase C: out[32x1024] = w @ V; wave d-cols [wv*128,+128) ----
        float sql[2][4];
        #pragma unroll
        for (int rf = 0; rf < 2; ++rf)
            #pragma unroll
            for (int r = 0; r < 4; ++r) sql[rf][r] = 0.f;
        uint32_t def[4][4];   // deferred rows 16-31, bf16-packed (r even | odd<<16)

        #pragma unroll 1
        for (int ch = 0; ch < 4; ++ch) {
            f32x4 acc2[2][2];
            #pragma unroll
            for (int rf = 0; rf < 2; ++rf)
                #pragma unroll
                for (int c2 = 0; c2 < 2; ++c2)
                    acc2[rf][c2] = (f32x4){0.f, 0.f, 0.f, 0.f};
            const __bf16* vt0 = Vt + (size_t)l * D * NSUP
                              + (size_t)(wv * 128 + ch * 32 + llo) * NSUP + lhi * 8;
            bf16x8 vb[4][2];
            #pragma unroll
            for (int p = 0; p < 3; ++p)
                #pragma unroll
                for (int c2 = 0; c2 < 2; ++c2)
                    vb[p][c2] = *(const bf16x8*)(vt0 + (size_t)c2 * 16 * NSUP + p * 32);
            #pragma unroll
            for (int k = 0; k < 8; ++k) {
                if (k < 5) {
                    #pragma unroll
                    for (int c2 = 0; c2 < 2; ++c2)
                        vb[(k + 3) & 3][c2] = *(const bf16x8*)(vt0 + (size_t)c2 * 16 * NSUP + (k + 3) * 32);
                }
                bf16x8 a0 = *(const bf16x8*)(pool + WBASE + llo * 512 + ((k * 64 + lhi * 16) ^ swzk));
                bf16x8 a1 = *(const bf16x8*)(pool + WBASE + (16 + llo) * 512 + ((k * 64 + lhi * 16) ^ swzk));
                #pragma unroll
                for (int c2 = 0; c2 < 2; ++c2) {
                    acc2[0][c2] = MFMA16(a0, vb[k & 3][c2], acc2[0][c2]);
                    acc2[1][c2] = MFMA16(a1, vb[k & 3][c2], acc2[1][c2]);
                }
            }
            #pragma unroll
            for (int rf = 0; rf < 2; ++rf)
                #pragma unroll
                for (int c2 = 0; c2 < 2; ++c2)
                    #pragma unroll
                    for (int r = 0; r < 4; ++r)
                        sql[rf][r] += acc2[rf][c2][r] * acc2[rf][c2][r];
            if (l < 3) {
                // rows 0-15 immediate; rows 16-31 packed for deferred write
                #pragma unroll
                for (int c2 = 0; c2 < 2; ++c2) {
                    #pragma unroll
                    for (int r = 0; r < 4; ++r) {
                        int row = lhi * 4 + r;
                        int col = wv * 128 + ch * 32 + c2 * 16 + llo;
                        *(__bf16*)(pool + row * 2048 + ((col * 2) ^ ((row & 7) << 4))) =
                            (__bf16)acc2[0][c2][r];
                    }
                    def[ch][c2 * 2 + 0] = bfbits(acc2[1][c2][0]) | (bfbits(acc2[1][c2][1]) << 16);
                    def[ch][c2 * 2 + 1] = bfbits(acc2[1][c2][2]) | (bfbits(acc2[1][c2][3]) << 16);
                }
            } else {
                #pragma unroll
                for (int rf = 0; rf < 2; ++rf)
                    #pragma unroll
                    for (int c2 = 0; c2 < 2; ++c2)
                        #pragma unroll
                        for (int r = 0; r < 4; ++r) {
                            int row = rf * 16 + lhi * 4 + r;
                            int col = wv * 128 + ch * 32 + c2 * 16 + llo;
                            out[(size_t)(row0 + row) * D + col] = acc2[rf][c2][r];
                        }
            }
        }

        if (l < 3) {
            __syncthreads();   // bar4: all w reads done -> w region dead
            #pragma unroll
            for (int rf = 0; rf < 2; ++rf)
                #pragma unroll
                for (int r = 0; r < 4; ++r) {
                    float s = sql[rf][r];
                    s += __shfl_xor(s, 1); s += __shfl_xor(s, 2);
                    s += __shfl_xor(s, 4); s += __shfl_xor(s, 8);
                    if (llo == 0)
                        *(float*)(pool + WBASE + (rf * 16 + lhi * 4 + r) * 32 + wv * 4) = s;
                }
            __syncthreads();   // bar5: sq partials visible
            #pragma unroll
            for (int rf = 0; rf < 2; ++rf)
                #pragma unroll
                for (int r = 0; r < 4; ++r) {
                    const f32x4* rp = (const f32x4*)(pool + WBASE + (rf * 16 + lhi * 4 + r) * 32);
                    f32x4 s0 = rp[0], s1 = rp[1];
                    float ss = (s0[0] + s0[1] + s0[2] + s0[3]) + (s1[0] + s1[1] + s1[2] + s1[3]);
                    rnv[rf][r] = 1.f / (sqrtf(ss) + 1e-9f);
                }
            __syncthreads();   // bar6: sq reads done -> region writable
            // deferred new-h rows 16-31 (includes old w region)
            #pragma unroll
            for (int ch = 0; ch < 4; ++ch)
                #pragma unroll
                for (int c2 = 0; c2 < 2; ++c2)
                    #pragma unroll
                    for (int rp = 0; rp < 2; ++rp) {
                        uint32_t pk = def[ch][c2 * 2 + rp];
                        int re = 16 + lhi * 4 + rp * 2;
                        int ro = re + 1;
                        int col = wv * 128 + ch * 32 + c2 * 16 + llo;
                        *(uint16_t*)(pool + re * 2048 + ((col * 2) ^ ((re & 7) << 4))) =
                            (uint16_t)(pk & 0xffff);
                        *(uint16_t*)(pool + ro * 2048 + ((col * 2) ^ ((ro & 7) << 4))) =
                            (uint16_t)(pk >> 16);
                    }
            __syncthreads();   // bar7: h complete for next layer
        }
    }
}

extern "C" void kernel_launch(void* const* d_in, const int* in_sizes, int n_in,
                              void* d_out, int out_size, void* d_ws, size_t ws_size,
                              hipStream_t stream) {
    const float* x = (const float*)d_in[0];
    const float* keys = (const float*)d_in[1];
    const float* values = (const float*)d_in[2];
    float* out = (float*)d_out;

    char* ws = (char*)d_ws;
    __bf16* Kb = (__bf16*)(ws);             // 4*256*1024*2 = 2 MB
    __bf16* Vt = (__bf16*)(ws + 2097152);   // 4*1024*256*2 = 2 MB

    cast_k_kernel<<<1024, 256, 0, stream>>>(keys, Kb);
    transpose_v_kernel<<<dim3(16, 4, 4), 256, 0, stream>>>(values, Vt);
    fused4_kernel<<<LGRID, LTHREADS, 0, stream>>>(x, out, Kb, Vt);
}